// Round 1
// baseline (1128.276 us; speedup 1.0000x reference)
//
#include <hip/hip_runtime.h>

#define CC   256   // channels
#define QKC  32    // q/k channels
#define NPIX 4096  // 64*64
#define NB   4     // batch
#define KB   64    // kv tile
#define PSTR 68    // padded P stride (b128-aligned, conflict-free)

// ---------------- QKV projection ----------------
// grid: NB*64 blocks, 256 threads. Block = (batch b, 64-pixel tile n0).
__global__ __launch_bounds__(256) void qkv_proj(
    const float* __restrict__ x,
    const float* __restrict__ wq, const float* __restrict__ bq,
    const float* __restrict__ wk, const float* __restrict__ bk,
    const float* __restrict__ wv, const float* __restrict__ bv,
    float* __restrict__ Qo, float* __restrict__ Ko, float* __restrict__ Vo)
{
    __shared__ float xs[CC][64];   // 64 KB
    const int t  = threadIdx.x;
    const int b  = blockIdx.x >> 6;
    const int n0 = (blockIdx.x & 63) << 6;

    {   // stage x tile [c][n_local], coalesced
        const int nl = t & 63;
        const int cb = t >> 6;
        const float* xp = x + ((size_t)b * CC) * NPIX + n0 + nl;
        #pragma unroll
        for (int i = 0; i < 64; ++i) {
            const int c = i * 4 + cb;
            xs[c][nl] = xp[(size_t)c * NPIX];
        }
    }
    __syncthreads();

    const int og = t & 31;        // v-channels og+32*i; q/k channel og
    const int p0 = (t >> 5) * 8;  // 8 pixels

    float accq[8], acck[8], accv[8][8];
    const float bqv = bq[og], bkv = bk[og];
    #pragma unroll
    for (int j = 0; j < 8; ++j) { accq[j] = bqv; acck[j] = bkv; }
    #pragma unroll
    for (int i = 0; i < 8; ++i) {
        const float bvv = bv[og + 32 * i];
        #pragma unroll
        for (int j = 0; j < 8; ++j) accv[i][j] = bvv;
    }

    const float4* wq4 = reinterpret_cast<const float4*>(wq + og * CC);
    const float4* wk4 = reinterpret_cast<const float4*>(wk + og * CC);

    for (int c4 = 0; c4 < CC / 4; ++c4) {
        float xv[4][8];
        #pragma unroll
        for (int cc = 0; cc < 4; ++cc) {
            const float4 a0 = *reinterpret_cast<const float4*>(&xs[c4 * 4 + cc][p0]);
            const float4 a1 = *reinterpret_cast<const float4*>(&xs[c4 * 4 + cc][p0 + 4]);
            xv[cc][0]=a0.x; xv[cc][1]=a0.y; xv[cc][2]=a0.z; xv[cc][3]=a0.w;
            xv[cc][4]=a1.x; xv[cc][5]=a1.y; xv[cc][6]=a1.z; xv[cc][7]=a1.w;
        }
        const float4 wqv = wq4[c4];
        const float4 wkv = wk4[c4];
        const float wqa[4] = {wqv.x, wqv.y, wqv.z, wqv.w};
        const float wka[4] = {wkv.x, wkv.y, wkv.z, wkv.w};
        #pragma unroll
        for (int cc = 0; cc < 4; ++cc) {
            #pragma unroll
            for (int j = 0; j < 8; ++j) {
                accq[j] += wqa[cc] * xv[cc][j];
                acck[j] += wka[cc] * xv[cc][j];
            }
        }
        #pragma unroll
        for (int i = 0; i < 8; ++i) {
            const float4 wvv = *reinterpret_cast<const float4*>(wv + (size_t)(og + 32 * i) * CC + c4 * 4);
            const float wva[4] = {wvv.x, wvv.y, wvv.z, wvv.w};
            #pragma unroll
            for (int cc = 0; cc < 4; ++cc) {
                #pragma unroll
                for (int j = 0; j < 8; ++j)
                    accv[i][j] += wva[cc] * xv[cc][j];
            }
        }
    }

    #pragma unroll
    for (int j = 0; j < 8; ++j) {
        const size_t n = (size_t)b * NPIX + n0 + p0 + j;
        Qo[n * QKC + og] = accq[j];
        Ko[n * QKC + og] = acck[j];
        float* vp = Vo + n * CC + og;
        #pragma unroll
        for (int i = 0; i < 8; ++i) vp[32 * i] = accv[i][j];
    }
}

// ---------------- flash attention + residual ----------------
// grid: 256 blocks (== CU count), 256 threads. Block = (b, 64 q-rows).
__global__ __launch_bounds__(256) void attn_kernel(
    const float* __restrict__ Qg, const float* __restrict__ Kg,
    const float* __restrict__ Vg, const float* __restrict__ x,
    const float* __restrict__ gamma, float* __restrict__ out)
{
    extern __shared__ float sm[];
    float* Kt   = sm;                 // [64][32]
    float* Vt   = sm + 64 * QKC;      // [64][256]  (reused as Ostage[256][64])
    float* Pt   = Vt + 64 * CC;       // [64][PSTR]
    float* mrun = Pt + 64 * PSTR;     // [64]
    float* lrun = mrun + 64;          // [64]
    float* alph = lrun + 64;          // [64]

    const int t = threadIdx.x;
    // XCD-chunked swizzle: each XCD gets 32 contiguous logical blocks (half a batch)
    const int l  = (blockIdx.x & 7) * 32 + (blockIdx.x >> 3);
    const int b  = l >> 6;
    const int n0 = (l & 63) << 6;

    const int r    = t >> 2;         // S-phase row
    const int msub = t & 3;          // S-phase m-quarter
    const int r0   = (t >> 5) * 8;   // PV rows
    const int c0   = (t & 31) * 8;   // PV cols

    if (t < 64) { mrun[t] = -1e30f; lrun[t] = 0.0f; }

    // q row in registers
    float q[32];
    {
        const float4* qp = reinterpret_cast<const float4*>(Qg + ((size_t)b * NPIX + n0 + r) * QKC);
        #pragma unroll
        for (int i = 0; i < 8; ++i) {
            const float4 v = qp[i];
            q[4*i] = v.x; q[4*i+1] = v.y; q[4*i+2] = v.z; q[4*i+3] = v.w;
        }
    }

    float O[8][8];
    #pragma unroll
    for (int jr = 0; jr < 8; ++jr)
        #pragma unroll
        for (int jc = 0; jc < 8; ++jc) O[jr][jc] = 0.0f;

    for (int m0 = 0; m0 < NPIX; m0 += KB) {
        __syncthreads();   // previous tile's consumers done
        {   // stage K tile [m][k]
            const int m = t >> 2, cb = (t & 3) * 8;
            const float4* src = reinterpret_cast<const float4*>(
                Kg + ((size_t)b * NPIX + m0 + m) * QKC + cb);
            const float4 a0 = src[0], a1 = src[1];
            float* dst = &Kt[m * QKC + cb];
            *reinterpret_cast<float4*>(dst)     = a0;
            *reinterpret_cast<float4*>(dst + 4) = a1;
        }
        {   // stage V tile [m][c]
            const float* vsrc = Vg + ((size_t)b * NPIX + m0) * CC;
            #pragma unroll
            for (int i = 0; i < 16; ++i) {
                const int f4 = (i * 256 + t) * 4;
                *reinterpret_cast<float4*>(&Vt[f4]) =
                    *reinterpret_cast<const float4*>(vsrc + f4);
            }
        }
        __syncthreads();

        // ---- S = q · K^T (16 m's per thread) ----
        float s[16];
        #pragma unroll
        for (int j = 0; j < 16; ++j) {
            const int m = msub * 16 + j;
            const float4* kr = reinterpret_cast<const float4*>(&Kt[m * QKC]);
            float acc = 0.0f;
            #pragma unroll
            for (int kk = 0; kk < 8; ++kk) {
                const float4 kv = kr[kk];
                acc += q[4*kk]*kv.x + q[4*kk+1]*kv.y + q[4*kk+2]*kv.z + q[4*kk+3]*kv.w;
            }
            s[j] = acc;
        }

        // ---- online softmax (4 lanes per row) ----
        float tmax = s[0];
        #pragma unroll
        for (int j = 1; j < 16; ++j) tmax = fmaxf(tmax, s[j]);
        tmax = fmaxf(tmax, __shfl_xor(tmax, 1));
        tmax = fmaxf(tmax, __shfl_xor(tmax, 2));
        const float mold = mrun[r];
        const float mnew = fmaxf(mold, tmax);
        const float al   = __expf(mold - mnew);
        float lsum = 0.0f;
        #pragma unroll
        for (int j = 0; j < 16; ++j) {
            const float p = __expf(s[j] - mnew);
            Pt[r * PSTR + msub * 16 + j] = p;
            lsum += p;
        }
        lsum += __shfl_xor(lsum, 1);
        lsum += __shfl_xor(lsum, 2);
        if (msub == 0) {
            mrun[r] = mnew;
            lrun[r] = al * lrun[r] + lsum;
            alph[r] = al;
        }
        __syncthreads();

        // ---- PV: O[8r][8c] += P · V ----
        float av[8];
        #pragma unroll
        for (int jr = 0; jr < 8; ++jr) av[jr] = alph[r0 + jr];
        #pragma unroll
        for (int jr = 0; jr < 8; ++jr)
            #pragma unroll
            for (int jc = 0; jc < 8; ++jc) O[jr][jc] *= av[jr];

        for (int mc = 0; mc < 16; ++mc) {
            float4 p4[8];
            #pragma unroll
            for (int jr = 0; jr < 8; ++jr)
                p4[jr] = *reinterpret_cast<const float4*>(&Pt[(r0 + jr) * PSTR + mc * 4]);
            #pragma unroll
            for (int mm = 0; mm < 4; ++mm) {
                const float4 v0 = *reinterpret_cast<const float4*>(&Vt[(mc*4+mm) * CC + c0]);
                const float4 v1 = *reinterpret_cast<const float4*>(&Vt[(mc*4+mm) * CC + c0 + 4]);
                #pragma unroll
                for (int jr = 0; jr < 8; ++jr) {
                    const float p = reinterpret_cast<const float*>(&p4[jr])[mm];
                    O[jr][0] += p * v0.x; O[jr][1] += p * v0.y;
                    O[jr][2] += p * v0.z; O[jr][3] += p * v0.w;
                    O[jr][4] += p * v1.x; O[jr][5] += p * v1.y;
                    O[jr][6] += p * v1.z; O[jr][7] += p * v1.w;
                }
            }
        }
    }

    // ---- epilogue: scale, restage through LDS, fused residual, coalesced out ----
    const float g = gamma[0];
    float linv[8];
    #pragma unroll
    for (int jr = 0; jr < 8; ++jr) linv[jr] = g / lrun[r0 + jr];
    __syncthreads();           // all PV reads of Vt done
    float* Ost = Vt;           // [256][64]
    #pragma unroll
    for (int jc = 0; jc < 8; ++jc) {
        float w[8];
        #pragma unroll
        for (int jr = 0; jr < 8; ++jr) w[jr] = O[jr][jc] * linv[jr];
        float* dst = &Ost[(c0 + jc) * 64 + r0];
        *reinterpret_cast<float4*>(dst)     = make_float4(w[0], w[1], w[2], w[3]);
        *reinterpret_cast<float4*>(dst + 4) = make_float4(w[4], w[5], w[6], w[7]);
    }
    __syncthreads();
    {
        const int nl = t & 63, cb = t >> 6;
        const float* xp = x + ((size_t)b * CC) * NPIX + n0 + nl;
        float*       op = out + ((size_t)b * CC) * NPIX + n0 + nl;
        #pragma unroll
        for (int i = 0; i < 64; ++i) {
            const int c = i * 4 + cb;
            op[(size_t)c * NPIX] = Ost[c * 64 + nl] + xp[(size_t)c * NPIX];
        }
    }
}

extern "C" void kernel_launch(void* const* d_in, const int* in_sizes, int n_in,
                              void* d_out, int out_size, void* d_ws, size_t ws_size,
                              hipStream_t stream) {
    const float* x     = (const float*)d_in[0];
    const float* wq    = (const float*)d_in[1];
    const float* bq    = (const float*)d_in[2];
    const float* wk    = (const float*)d_in[3];
    const float* bk    = (const float*)d_in[4];
    const float* wv    = (const float*)d_in[5];
    const float* bv    = (const float*)d_in[6];
    const float* gamma = (const float*)d_in[7];
    float* out = (float*)d_out;

    // workspace: Q [B][N][32] | K [B][N][32] | V [B][N][256]  (f32, 20 MB)
    float* Q = (float*)d_ws;
    float* K = Q + (size_t)NB * NPIX * QKC;
    float* V = K + (size_t)NB * NPIX * QKC;

    hipLaunchKernelGGL(qkv_proj, dim3(NB * 64), dim3(256), 0, stream,
                       x, wq, bq, wk, bk, wv, bv, Q, K, V);

    const int smem_bytes = (64 * QKC + 64 * CC + 64 * PSTR + 192) * 4;  // ~92 KB
    hipFuncSetAttribute(reinterpret_cast<const void*>(attn_kernel),
                        hipFuncAttributeMaxDynamicSharedMemorySize, smem_bytes);
    hipLaunchKernelGGL(attn_kernel, dim3(256), dim3(256), smem_bytes, stream,
                       Q, K, V, x, gamma, out);
}

// Round 3
// 201.506 us; speedup vs baseline: 5.5992x; 5.5992x over previous
//
#include <hip/hip_runtime.h>
#include <hip/hip_fp16.h>

#define CC   256
#define QKC  32
#define NPIX 4096
#define NB   4

typedef __attribute__((ext_vector_type(8))) _Float16 f16x8;
typedef __attribute__((ext_vector_type(4))) float     f32x4;

// ---------------- QKV projection (f32 compute, f16 outputs) ----------------
// grid: NB*64 blocks, 256 threads. Block = (batch b, 64-pixel tile n0).
// Outputs: Qh,Kh [B][N][32] f16 ; VTh [B][C][N] f16 (transposed!)
__global__ __launch_bounds__(256) void qkv_proj(
    const float* __restrict__ x,
    const float* __restrict__ wq, const float* __restrict__ bq,
    const float* __restrict__ wk, const float* __restrict__ bk,
    const float* __restrict__ wv, const float* __restrict__ bv,
    __half* __restrict__ Qh, __half* __restrict__ Kh, __half* __restrict__ VTh)
{
    extern __shared__ float sm[];
    float*  xs = sm;                         // [256][64] f32, 64 KB
    __half* vt = (__half*)(sm + CC * 64);    // [256][64] f16, 32 KB

    const int t  = threadIdx.x;
    const int b  = blockIdx.x >> 6;
    const int n0 = (blockIdx.x & 63) << 6;

    {   // stage x tile [c][n_local], coalesced
        const int nl = t & 63;
        const int cb = t >> 6;
        const float* xp = x + ((size_t)b * CC) * NPIX + n0 + nl;
        #pragma unroll
        for (int i = 0; i < 64; ++i) {
            const int c = i * 4 + cb;
            xs[c * 64 + nl] = xp[(size_t)c * NPIX];
        }
    }
    __syncthreads();

    const int og = t & 31;        // v-channels og+32*i; q/k channel og
    const int p0 = (t >> 5) * 8;  // 8 pixels

    float accq[8], acck[8], accv[8][8];
    const float bqv = bq[og], bkv = bk[og];
    #pragma unroll
    for (int j = 0; j < 8; ++j) { accq[j] = bqv; acck[j] = bkv; }
    #pragma unroll
    for (int i = 0; i < 8; ++i) {
        const float bvv = bv[og + 32 * i];
        #pragma unroll
        for (int j = 0; j < 8; ++j) accv[i][j] = bvv;
    }

    const float4* wq4 = reinterpret_cast<const float4*>(wq + og * CC);
    const float4* wk4 = reinterpret_cast<const float4*>(wk + og * CC);

    for (int c4 = 0; c4 < CC / 4; ++c4) {
        float xv[4][8];
        #pragma unroll
        for (int cc = 0; cc < 4; ++cc) {
            const float4 a0 = *reinterpret_cast<const float4*>(&xs[(c4 * 4 + cc) * 64 + p0]);
            const float4 a1 = *reinterpret_cast<const float4*>(&xs[(c4 * 4 + cc) * 64 + p0 + 4]);
            xv[cc][0]=a0.x; xv[cc][1]=a0.y; xv[cc][2]=a0.z; xv[cc][3]=a0.w;
            xv[cc][4]=a1.x; xv[cc][5]=a1.y; xv[cc][6]=a1.z; xv[cc][7]=a1.w;
        }
        const float4 wqv = wq4[c4];
        const float4 wkv = wk4[c4];
        const float wqa[4] = {wqv.x, wqv.y, wqv.z, wqv.w};
        const float wka[4] = {wkv.x, wkv.y, wkv.z, wkv.w};
        #pragma unroll
        for (int cc = 0; cc < 4; ++cc) {
            #pragma unroll
            for (int j = 0; j < 8; ++j) {
                accq[j] += wqa[cc] * xv[cc][j];
                acck[j] += wka[cc] * xv[cc][j];
            }
        }
        #pragma unroll
        for (int i = 0; i < 8; ++i) {
            const float4 wvv = *reinterpret_cast<const float4*>(wv + (size_t)(og + 32 * i) * CC + c4 * 4);
            const float wva[4] = {wvv.x, wvv.y, wvv.z, wvv.w};
            #pragma unroll
            for (int cc = 0; cc < 4; ++cc) {
                #pragma unroll
                for (int j = 0; j < 8; ++j)
                    accv[i][j] += wva[cc] * xv[cc][j];
            }
        }
    }

    // Q/K writes: f16, [n][32] layout
    #pragma unroll
    for (int j = 0; j < 8; ++j) {
        const size_t n = (size_t)b * NPIX + n0 + p0 + j;
        Qh[n * QKC + og] = __float2half(accq[j]);
        Kh[n * QKC + og] = __float2half(acck[j]);
    }

    // V transpose via LDS: write [c][n_local] f16 pairs, then coalesced 16B stores
    #pragma unroll
    for (int i = 0; i < 8; ++i) {
        #pragma unroll
        for (int j2 = 0; j2 < 4; ++j2) {
            __half2 h = __floats2half2_rn(accv[i][2 * j2], accv[i][2 * j2 + 1]);
            *reinterpret_cast<__half2*>(&vt[(og + 32 * i) * 64 + p0 + 2 * j2]) = h;
        }
    }
    __syncthreads();
    #pragma unroll
    for (int k = 0; k < 8; ++k) {
        const int G = t + 256 * k;
        const int c = G >> 3;
        const int g = G & 7;
        const uint4 u = *reinterpret_cast<const uint4*>(&vt[c * 64 + g * 8]);
        *reinterpret_cast<uint4*>(VTh + ((size_t)(b * CC + c)) * NPIX + n0 + g * 8) = u;
    }
}

// ---------------- MFMA flash attention ----------------
// grid: 256 blocks x 512 threads (8 waves). Block = (b, 64 q rows).
// Wave w: S^T for qtile (w&3) [duplicated x2], PV for c rows [32w, 32w+32).
__global__ __launch_bounds__(512) void attn_mfma(
    const __half* __restrict__ Qh, const __half* __restrict__ Kh,
    const __half* __restrict__ VTh, const float* __restrict__ x,
    const float* __restrict__ gamma, float* __restrict__ out)
{
    __shared__ uint4 Praw[2][512];      // 2 x [64 q][128B] swizzled f16 P
    __shared__ float abuf[2][64];
    __shared__ float lbuf[64];

    const int t  = threadIdx.x;
    const int w  = t >> 6;
    const int l  = t & 63;
    const int lr = l & 15;
    const int s  = l >> 4;
    const int qt_own = w & 3;

    // XCD-chunked swizzle: each XCD owns 32 contiguous logical blocks
    const int blk = (blockIdx.x & 7) * 32 + (blockIdx.x >> 3);
    const int b  = blk >> 6;
    const int n0 = (blk & 63) << 6;

    // Q B-fragment (held whole kernel): lane holds Q[q=qt_own*16+lr][k=s*8+j]
    const f16x8 qfrag = *reinterpret_cast<const f16x8*>(
        Qh + ((size_t)b * NPIX + n0 + qt_own * 16 + lr) * QKC + s * 8);

    const __half* vbase = VTh + ((size_t)(b * CC + w * 32 + lr)) * NPIX + s * 8;
    const __half* kbase = Kh + ((size_t)b * NPIX + lr) * QKC + s * 8;

    f32x4 O[2][4];
    #pragma unroll
    for (int ct = 0; ct < 2; ++ct)
        #pragma unroll
        for (int qt = 0; qt < 4; ++qt)
            O[ct][qt] = (f32x4){0.f, 0.f, 0.f, 0.f};

    float m_run = -1e30f, l_run = 0.f;
    int buf = 0;

    // P write address pieces (swizzle: granule ^= q&7)
    const int qw    = qt_own * 16 + lr;          // q row this wave writes
    const int wsub  = (s & 1) * 8;               // byte within granule
    unsigned char* const pb0 = (unsigned char*)&Praw[0][0];
    unsigned char* const pb1 = (unsigned char*)&Praw[1][0];

    for (int step = 0; step < NPIX / 64; ++step) {
        const int m0 = step * 64;

        // ---- prefetch V^T A-fragments (global, L2-resident) ----
        f16x8 vfrag[2][2];
        #pragma unroll
        for (int ct = 0; ct < 2; ++ct)
            #pragma unroll
            for (int ks = 0; ks < 2; ++ks)
                vfrag[ct][ks] = *reinterpret_cast<const f16x8*>(
                    vbase + (size_t)ct * 16 * NPIX + m0 + ks * 32);

        // ---- S^T = K · Q^T : 4 MFMAs ----
        f32x4 sacc[4];
        #pragma unroll
        for (int mt = 0; mt < 4; ++mt) {
            const f16x8 kf = *reinterpret_cast<const f16x8*>(
                kbase + (size_t)(m0 + mt * 16) * QKC);
            sacc[mt] = __builtin_amdgcn_mfma_f32_16x16x32_f16(
                kf, qfrag, (f32x4){0.f, 0.f, 0.f, 0.f}, 0, 0, 0);
        }

        // ---- online softmax (per lane: q = qt_own*16+lr, 16 m values) ----
        float tmax = sacc[0][0];
        #pragma unroll
        for (int mt = 0; mt < 4; ++mt)
            #pragma unroll
            for (int r = 0; r < 4; ++r)
                tmax = fmaxf(tmax, sacc[mt][r]);
        tmax = fmaxf(tmax, __shfl_xor(tmax, 16));
        tmax = fmaxf(tmax, __shfl_xor(tmax, 32));
        const float mnew = fmaxf(m_run, tmax);
        const float al   = __expf(m_run - mnew);
        float p[4][4];
        float lsum = 0.f;
        #pragma unroll
        for (int mt = 0; mt < 4; ++mt)
            #pragma unroll
            for (int r = 0; r < 4; ++r) {
                p[mt][r] = __expf(sacc[mt][r] - mnew);
                lsum += p[mt][r];
            }
        lsum += __shfl_xor(lsum, 16);
        lsum += __shfl_xor(lsum, 32);
        l_run = al * l_run + lsum;
        m_run = mnew;

        // ---- pack P -> f16, swizzled LDS write (waves 0..3 only) ----
        if (w < 4) {
            unsigned char* pb = buf ? pb1 : pb0;
            #pragma unroll
            for (int mt = 0; mt < 4; ++mt) {
                const int g = (((s >> 1) + 2 * mt) ^ (qw & 7));
                const __half2 u0 = __floats2half2_rn(p[mt][0], p[mt][1]);
                const __half2 u1 = __floats2half2_rn(p[mt][2], p[mt][3]);
                *reinterpret_cast<__half2*>(pb + qw * 128 + g * 16 + wsub)     = u0;
                *reinterpret_cast<__half2*>(pb + qw * 128 + g * 16 + wsub + 4) = u1;
            }
            if (l < 16) abuf[buf][qw] = al;
        }
        __syncthreads();

        // ---- rescale O by alpha ----
        float av[4];
        #pragma unroll
        for (int qt = 0; qt < 4; ++qt) av[qt] = abuf[buf][qt * 16 + lr];
        #pragma unroll
        for (int ct = 0; ct < 2; ++ct)
            #pragma unroll
            for (int qt = 0; qt < 4; ++qt)
                #pragma unroll
                for (int r = 0; r < 4; ++r)
                    O[ct][qt][r] *= av[qt];

        // ---- read P B-fragments, swizzled ----
        const unsigned char* pr = buf ? pb1 : pb0;
        f16x8 pf[4][2];
        #pragma unroll
        for (int qt = 0; qt < 4; ++qt) {
            const int q2 = qt * 16 + lr;
            #pragma unroll
            for (int ks = 0; ks < 2; ++ks) {
                const int g = ((s + 4 * ks) ^ (q2 & 7));
                pf[qt][ks] = *reinterpret_cast<const f16x8*>(pr + q2 * 128 + g * 16);
            }
        }

        // ---- O^T += V^T · P^T : 16 MFMAs ----
        #pragma unroll
        for (int ks = 0; ks < 2; ++ks)
            #pragma unroll
            for (int ct = 0; ct < 2; ++ct)
                #pragma unroll
                for (int qt = 0; qt < 4; ++qt)
                    O[ct][qt] = __builtin_amdgcn_mfma_f32_16x16x32_f16(
                        vfrag[ct][ks], pf[qt][ks], O[ct][qt], 0, 0, 0);

        buf ^= 1;
    }

    // ---- epilogue: publish l, fused gamma/residual, direct stores ----
    if (w < 4 && l < 16) lbuf[qw] = l_run;
    __syncthreads();
    const float g = gamma[0];
    float linv[4];
    #pragma unroll
    for (int qt = 0; qt < 4; ++qt) linv[qt] = g / lbuf[qt * 16 + lr];

    #pragma unroll
    for (int ct = 0; ct < 2; ++ct) {
        #pragma unroll
        for (int qt = 0; qt < 4; ++qt) {
            #pragma unroll
            for (int r = 0; r < 4; ++r) {
                const int c = w * 32 + ct * 16 + s * 4 + r;
                const size_t idx = ((size_t)(b * CC + c)) * NPIX + n0 + qt * 16 + lr;
                out[idx] = O[ct][qt][r] * linv[qt] + x[idx];
            }
        }
    }
}

extern "C" void kernel_launch(void* const* d_in, const int* in_sizes, int n_in,
                              void* d_out, int out_size, void* d_ws, size_t ws_size,
                              hipStream_t stream) {
    const float* x     = (const float*)d_in[0];
    const float* wq    = (const float*)d_in[1];
    const float* bq    = (const float*)d_in[2];
    const float* wk    = (const float*)d_in[3];
    const float* bk    = (const float*)d_in[4];
    const float* wv    = (const float*)d_in[5];
    const float* bv    = (const float*)d_in[6];
    const float* gamma = (const float*)d_in[7];
    float* out = (float*)d_out;

    // workspace (f16): Qh [B][N][32] | Kh [B][N][32] | VTh [B][C][N]  (10 MB)
    __half* Qh  = (__half*)d_ws;
    __half* Kh  = Qh + (size_t)NB * NPIX * QKC;
    __half* VTh = Kh + (size_t)NB * NPIX * QKC;

    const int qkv_smem = (CC * 64) * 4 + (CC * 64) * 2;   // 96 KB dynamic
    (void)hipFuncSetAttribute(reinterpret_cast<const void*>(qkv_proj),
                              hipFuncAttributeMaxDynamicSharedMemorySize, qkv_smem);
    hipLaunchKernelGGL(qkv_proj, dim3(NB * 64), dim3(256), qkv_smem, stream,
                       x, wq, bq, wk, bk, wv, bv, Qh, Kh, VTh);

    hipLaunchKernelGGL(attn_mfma, dim3(256), dim3(512), 0, stream,
                       Qh, Kh, VTh, x, gamma, out);
}

// Round 4
// 163.329 us; speedup vs baseline: 6.9080x; 1.2337x over previous
//
#include <hip/hip_runtime.h>
#include <hip/hip_fp16.h>

#define CC   256
#define QKC  32
#define NPIX 4096
#define NB   4

typedef __attribute__((ext_vector_type(8))) _Float16 f16x8;
typedef __attribute__((ext_vector_type(4))) float     f32x4;

static __device__ __forceinline__ unsigned h2bits(__half2 h) {
    union { __half2 h; unsigned u; } cv; cv.h = h; return cv.u;
}

// ---------------- wv transpose: wvT[c][o] = wv[o][c] ----------------
__global__ __launch_bounds__(256) void wv_transpose(
    const float* __restrict__ wv, float* __restrict__ wvT)
{
    __shared__ float tile[16][17];
    const int tx = threadIdx.x & 15, ty = threadIdx.x >> 4;
    const int ti = blockIdx.x & 15, tj = blockIdx.x >> 4;
    tile[ty][tx] = wv[(tj * 16 + ty) * 256 + ti * 16 + tx];
    __syncthreads();
    wvT[(ti * 16 + ty) * 256 + tj * 16 + tx] = tile[tx][ty];
}

// ---------------- QKV projection (f32 compute, f16 outputs) ----------------
// grid: NB*128 blocks (32-pixel tiles), 256 threads.
// thread: og = t&31 (q/k channel og; v channels og*8..og*8+7), pixels p0=(t>>5)*4.
__global__ __launch_bounds__(256) void qkv_proj(
    const float* __restrict__ x,
    const float* __restrict__ wq, const float* __restrict__ bq,
    const float* __restrict__ wk, const float* __restrict__ bk,
    const float* __restrict__ wvT, const float* __restrict__ bv,
    __half* __restrict__ Qh, __half* __restrict__ Kh, __half* __restrict__ VTh)
{
    __shared__ float  xs[CC * 32];     // [c][n] 32 KB
    __shared__ __half vt[32 * CC];     // [n][c] 16 KB

    const int t  = threadIdx.x;
    const int b  = blockIdx.x >> 7;
    const int n0 = (blockIdx.x & 127) << 5;

    {   // stage x tile [c][nl]
        const int nl = t & 31, cg = t >> 5;
        const float* xp = x + ((size_t)b * CC) * NPIX + n0 + nl;
        #pragma unroll
        for (int i = 0; i < 32; ++i) {
            const int c = cg + 8 * i;
            xs[c * 32 + nl] = xp[(size_t)c * NPIX];
        }
    }
    __syncthreads();

    const int og = t & 31;
    const int p0 = (t >> 5) * 4;

    float accq[4], acck[4], accv[8][4];
    {
        const float bqv = bq[og], bkv = bk[og];
        #pragma unroll
        for (int j = 0; j < 4; ++j) { accq[j] = bqv; acck[j] = bkv; }
        #pragma unroll
        for (int i = 0; i < 8; ++i) {
            const float bvv = bv[og * 8 + i];
            #pragma unroll
            for (int j = 0; j < 4; ++j) accv[i][j] = bvv;
        }
    }

    const float4* wq4 = reinterpret_cast<const float4*>(wq + og * CC);
    const float4* wk4 = reinterpret_cast<const float4*>(wk + og * CC);

    float4 pw_q[2], pw_k[2], pw_v[2][8];

    // prologue: load weights for c4=0 into slot 0
    pw_q[0] = wq4[0]; pw_k[0] = wk4[0];
    #pragma unroll
    for (int cc = 0; cc < 4; ++cc) {
        const float4* wp = reinterpret_cast<const float4*>(wvT + (size_t)cc * 256 + og * 8);
        pw_v[0][cc * 2] = wp[0]; pw_v[0][cc * 2 + 1] = wp[1];
    }

#define QKV_BODY(CUR, NXT, C4)                                                      \
    {                                                                               \
        if ((C4) < 63) {                                                            \
            pw_q[NXT] = wq4[(C4) + 1]; pw_k[NXT] = wk4[(C4) + 1];                   \
            _Pragma("unroll")                                                       \
            for (int cc = 0; cc < 4; ++cc) {                                        \
                const float4* wp = reinterpret_cast<const float4*>(                 \
                    wvT + (size_t)(((C4) + 1) * 4 + cc) * 256 + og * 8);            \
                pw_v[NXT][cc * 2] = wp[0]; pw_v[NXT][cc * 2 + 1] = wp[1];           \
            }                                                                       \
        }                                                                           \
        const float wqa[4] = {pw_q[CUR].x, pw_q[CUR].y, pw_q[CUR].z, pw_q[CUR].w};  \
        const float wka[4] = {pw_k[CUR].x, pw_k[CUR].y, pw_k[CUR].z, pw_k[CUR].w};  \
        _Pragma("unroll")                                                           \
        for (int cc = 0; cc < 4; ++cc) {                                            \
            const float4 xv = *reinterpret_cast<const float4*>(                     \
                &xs[((C4) * 4 + cc) * 32 + p0]);                                    \
            const float xa[4] = {xv.x, xv.y, xv.z, xv.w};                           \
            _Pragma("unroll")                                                       \
            for (int j = 0; j < 4; ++j) {                                           \
                accq[j] += wqa[cc] * xa[j];                                         \
                acck[j] += wka[cc] * xa[j];                                         \
            }                                                                       \
            const float4 wv0 = pw_v[CUR][cc * 2];                                   \
            const float4 wv1 = pw_v[CUR][cc * 2 + 1];                               \
            const float wva[8] = {wv0.x, wv0.y, wv0.z, wv0.w,                       \
                                  wv1.x, wv1.y, wv1.z, wv1.w};                      \
            _Pragma("unroll")                                                       \
            for (int i = 0; i < 8; ++i)                                             \
                _Pragma("unroll")                                                   \
                for (int j = 0; j < 4; ++j)                                         \
                    accv[i][j] += wva[i] * xa[j];                                   \
        }                                                                           \
    }

    for (int c4 = 0; c4 < 64; c4 += 2) {
        QKV_BODY(0, 1, c4)
        QKV_BODY(1, 0, c4 + 1)
    }
#undef QKV_BODY

    // Q/K writes: f16, [n][32]
    #pragma unroll
    for (int j = 0; j < 4; ++j) {
        const size_t n = (size_t)b * NPIX + n0 + p0 + j;
        Qh[n * QKC + og] = __float2half(accq[j]);
        Kh[n * QKC + og] = __float2half(acck[j]);
    }

    // V: write [n][c] LDS (b128), then per-thread c-row to global (64B runs)
    #pragma unroll
    for (int j = 0; j < 4; ++j) {
        uint4 u;
        u.x = h2bits(__floats2half2_rn(accv[0][j], accv[1][j]));
        u.y = h2bits(__floats2half2_rn(accv[2][j], accv[3][j]));
        u.z = h2bits(__floats2half2_rn(accv[4][j], accv[5][j]));
        u.w = h2bits(__floats2half2_rn(accv[6][j], accv[7][j]));
        *reinterpret_cast<uint4*>(&vt[(p0 + j) * CC + og * 8]) = u;
    }
    __syncthreads();
    {
        const int c = t;
        __half hb[32];
        #pragma unroll
        for (int n = 0; n < 32; ++n) hb[n] = vt[n * CC + c];
        __half* dst = VTh + ((size_t)(b * CC + c)) * NPIX + n0;
        #pragma unroll
        for (int k = 0; k < 4; ++k) {
            uint4 u;
            u.x = h2bits(__halves2half2(hb[8*k+0], hb[8*k+1]));
            u.y = h2bits(__halves2half2(hb[8*k+2], hb[8*k+3]));
            u.z = h2bits(__halves2half2(hb[8*k+4], hb[8*k+5]));
            u.w = h2bits(__halves2half2(hb[8*k+6], hb[8*k+7]));
            *reinterpret_cast<uint4*>(dst + 8 * k) = u;
        }
    }
}

// ---------------- MFMA flash attention, role-split waves ----------------
// grid: 256 blocks x 1024 threads (16 waves). Block = (b, 64 q rows).
// Waves 0-3: S^T + softmax for qtile w (pipelined one tile ahead).
// Waves 4-15: PV only; waves 4-7 own 2 c-tiles, 8-15 own 1.
__global__ __launch_bounds__(1024, 4) void attn_mfma(
    const __half* __restrict__ Qh, const __half* __restrict__ Kh,
    const __half* __restrict__ VTh, const float* __restrict__ x,
    const float* __restrict__ gamma, float* __restrict__ out)
{
    __shared__ unsigned char Praw[2][64 * 128];   // P f16, swizzled, dbuf (16 KB)
    __shared__ float abuf[2][64];
    __shared__ float lbuf[64];

    const int t  = threadIdx.x;
    const int w  = t >> 6;
    const int l  = t & 63;
    const int lr = l & 15;
    const int s  = l >> 4;

    const int blk = (blockIdx.x & 7) * 32 + (blockIdx.x >> 3);
    const int b  = blk >> 6;
    const int n0 = (blk & 63) << 6;

    // ---- S-wave state ----
    const int qw = w * 16 + lr;                  // q row (valid for w<4)
    f16x8 qfrag;
    f16x8 kf[4];
    float m_run = -1e30f, l_run = 0.f;
    const __half* kbase = Kh + ((size_t)b * NPIX + lr) * QKC + s * 8;

    // ---- PV-wave state ----
    const int nct   = (w < 8) ? 2 : 1;
    const int cbase = (w < 8) ? 32 * (w - 4) : 128 + 16 * (w - 8);
    const __half* vbase = VTh + ((size_t)(b * CC + cbase) + lr) * NPIX + s * 8;
    f16x8 vfc[2][2], vfn[2][2];
    f32x4 O[2][4];
    #pragma unroll
    for (int ct = 0; ct < 2; ++ct)
        #pragma unroll
        for (int qt = 0; qt < 4; ++qt)
            O[ct][qt] = (f32x4){0.f, 0.f, 0.f, 0.f};

    auto do_softmax = [&](int bw) {     // uses kf (current K tile), writes P+abuf[bw]
        f32x4 sacc[4];
        #pragma unroll
        for (int mt = 0; mt < 4; ++mt)
            sacc[mt] = __builtin_amdgcn_mfma_f32_16x16x32_f16(
                kf[mt], qfrag, (f32x4){0.f, 0.f, 0.f, 0.f}, 0, 0, 0);
        float tmax = sacc[0][0];
        #pragma unroll
        for (int mt = 0; mt < 4; ++mt)
            #pragma unroll
            for (int r = 0; r < 4; ++r) tmax = fmaxf(tmax, sacc[mt][r]);
        tmax = fmaxf(tmax, __shfl_xor(tmax, 16));
        tmax = fmaxf(tmax, __shfl_xor(tmax, 32));
        const float mnew = fmaxf(m_run, tmax);
        const float al   = __expf(m_run - mnew);
        float p[4][4];
        float lsum = 0.f;
        #pragma unroll
        for (int mt = 0; mt < 4; ++mt)
            #pragma unroll
            for (int r = 0; r < 4; ++r) {
                p[mt][r] = __expf(sacc[mt][r] - mnew);
                lsum += p[mt][r];
            }
        lsum += __shfl_xor(lsum, 16);
        lsum += __shfl_xor(lsum, 32);
        l_run = al * l_run + lsum;
        m_run = mnew;
        unsigned char* pb = &Praw[bw][0];
        #pragma unroll
        for (int mt = 0; mt < 4; ++mt) {
            const int g = ((s >> 1) + 2 * mt) ^ (qw & 7);
            const __half2 u0 = __floats2half2_rn(p[mt][0], p[mt][1]);
            const __half2 u1 = __floats2half2_rn(p[mt][2], p[mt][3]);
            *reinterpret_cast<__half2*>(pb + qw * 128 + g * 16 + (s & 1) * 8)     = u0;
            *reinterpret_cast<__half2*>(pb + qw * 128 + g * 16 + (s & 1) * 8 + 4) = u1;
        }
        if (l < 16) abuf[bw][qw] = al;
    };

    // ---- prologue ----
    if (w < 4) {
        qfrag = *reinterpret_cast<const f16x8*>(
            Qh + ((size_t)b * NPIX + n0 + qw) * QKC + s * 8);
        #pragma unroll
        for (int mt = 0; mt < 4; ++mt)
            kf[mt] = *reinterpret_cast<const f16x8*>(kbase + (size_t)(mt * 16) * QKC);
        do_softmax(0);                        // P(0) -> buf 0
        #pragma unroll
        for (int mt = 0; mt < 4; ++mt)        // preload K tile 1
            kf[mt] = *reinterpret_cast<const f16x8*>(kbase + (size_t)(64 + mt * 16) * QKC);
    } else {
        #pragma unroll
        for (int ct = 0; ct < 2; ++ct)
            if (ct < nct)
                #pragma unroll
                for (int ks = 0; ks < 2; ++ks)
                    vfc[ct][ks] = *reinterpret_cast<const f16x8*>(
                        vbase + (size_t)ct * 16 * NPIX + ks * 32);
    }
    __syncthreads();

    // ---- main loop: PV(t) with P[buf], softmax(t+1) -> P[buf^1] ----
    for (int step = 0; step < 64; ++step) {
        const int pbuf = step & 1;
        if (w < 4) {
            if (step < 63) {
                do_softmax(pbuf ^ 1);
                if (step < 62) {
                    const size_t moff = (size_t)((step + 2) * 64) * QKC;
                    #pragma unroll
                    for (int mt = 0; mt < 4; ++mt)
                        kf[mt] = *reinterpret_cast<const f16x8*>(
                            kbase + moff + (size_t)(mt * 16) * QKC);
                }
            }
        } else {
            if (step < 63) {
                const size_t moff = (size_t)((step + 1) * 64);
                #pragma unroll
                for (int ct = 0; ct < 2; ++ct)
                    if (ct < nct)
                        #pragma unroll
                        for (int ks = 0; ks < 2; ++ks)
                            vfn[ct][ks] = *reinterpret_cast<const f16x8*>(
                                vbase + (size_t)ct * 16 * NPIX + moff + ks * 32);
            }
            float av[4];
            #pragma unroll
            for (int qt = 0; qt < 4; ++qt) av[qt] = abuf[pbuf][qt * 16 + lr];
            #pragma unroll
            for (int ct = 0; ct < 2; ++ct)
                if (ct < nct)
                    #pragma unroll
                    for (int qt = 0; qt < 4; ++qt)
                        #pragma unroll
                        for (int r = 0; r < 4; ++r) O[ct][qt][r] *= av[qt];

            const unsigned char* pr = &Praw[pbuf][0];
            #pragma unroll
            for (int qt = 0; qt < 4; ++qt) {
                const int q2 = qt * 16 + lr;
                const int g0 = s ^ (q2 & 7);
                const int g1 = (s + 4) ^ (q2 & 7);
                const f16x8 pf0 = *reinterpret_cast<const f16x8*>(pr + q2 * 128 + g0 * 16);
                const f16x8 pf1 = *reinterpret_cast<const f16x8*>(pr + q2 * 128 + g1 * 16);
                #pragma unroll
                for (int ct = 0; ct < 2; ++ct)
                    if (ct < nct) {
                        O[ct][qt] = __builtin_amdgcn_mfma_f32_16x16x32_f16(
                            vfc[ct][0], pf0, O[ct][qt], 0, 0, 0);
                        O[ct][qt] = __builtin_amdgcn_mfma_f32_16x16x32_f16(
                            vfc[ct][1], pf1, O[ct][qt], 0, 0, 0);
                    }
            }
            if (step < 63) {
                #pragma unroll
                for (int ct = 0; ct < 2; ++ct)
                    #pragma unroll
                    for (int ks = 0; ks < 2; ++ks) vfc[ct][ks] = vfn[ct][ks];
            }
        }
        __syncthreads();
    }

    // ---- epilogue ----
    if (w < 4) { if (l < 16) lbuf[qw] = l_run; }
    __syncthreads();
    if (w >= 4) {
        const float g = gamma[0];
        float linv[4];
        #pragma unroll
        for (int qt = 0; qt < 4; ++qt) linv[qt] = g / lbuf[qt * 16 + lr];
        #pragma unroll
        for (int ct = 0; ct < 2; ++ct)
            if (ct < nct)
                #pragma unroll
                for (int qt = 0; qt < 4; ++qt)
                    #pragma unroll
                    for (int r = 0; r < 4; ++r) {
                        const int c = cbase + ct * 16 + s * 4 + r;
                        const size_t idx = ((size_t)(b * CC + c)) * NPIX + n0 + qt * 16 + lr;
                        out[idx] = O[ct][qt][r] * linv[qt] + x[idx];
                    }
    }
}

extern "C" void kernel_launch(void* const* d_in, const int* in_sizes, int n_in,
                              void* d_out, int out_size, void* d_ws, size_t ws_size,
                              hipStream_t stream) {
    const float* x     = (const float*)d_in[0];
    const float* wq    = (const float*)d_in[1];
    const float* bq    = (const float*)d_in[2];
    const float* wk    = (const float*)d_in[3];
    const float* bk    = (const float*)d_in[4];
    const float* wv    = (const float*)d_in[5];
    const float* bv    = (const float*)d_in[6];
    const float* gamma = (const float*)d_in[7];
    float* out = (float*)d_out;

    // ws: wvT (f32, 256 KB) | Qh (f16, 1 MB) | Kh (f16, 1 MB) | VTh (f16, 8 MB)
    float*  wvT = (float*)d_ws;
    __half* Qh  = (__half*)(wvT + 256 * 256);
    __half* Kh  = Qh + (size_t)NB * NPIX * QKC;
    __half* VTh = Kh + (size_t)NB * NPIX * QKC;

    hipLaunchKernelGGL(wv_transpose, dim3(256), dim3(256), 0, stream, wv, wvT);
    hipLaunchKernelGGL(qkv_proj, dim3(NB * 128), dim3(256), 0, stream,
                       x, wq, bq, wk, bk, wvT, bv, Qh, Kh, VTh);
    hipLaunchKernelGGL(attn_mfma, dim3(256), dim3(1024), 0, stream,
                       Qh, Kh, VTh, x, gamma, out);
}

// Round 5
// 100.992 us; speedup vs baseline: 11.1719x; 1.6172x over previous
//
#include <hip/hip_runtime.h>
#include <hip/hip_fp16.h>

#define CC   256
#define QKC  32
#define NPIX 4096
#define NB   4
#define XSTR 264          // xT row stride in halves (16B-aligned rows, spread banks)
#define VSTR 72           // vres row stride in halves

typedef __attribute__((ext_vector_type(8))) _Float16 f16x8;
typedef __attribute__((ext_vector_type(4))) float     f32x4;

// ---------------- W prep: Wh[320][256] f16 = [wv(256); wq(32); wk(32)] ----------------
__global__ __launch_bounds__(256) void wh_prep(
    const float* __restrict__ wq, const float* __restrict__ wk,
    const float* __restrict__ wv, __half* __restrict__ Wh)
{
    const int idx4 = blockIdx.x * 256 + threadIdx.x;   // 0..20479 float4s
    const int o  = idx4 >> 6;                          // 0..319
    const int cw = (idx4 & 63) << 2;
    const float* src;
    if (o < 256)      src = wv + (size_t)o * 256 + cw;
    else if (o < 288) src = wq + (size_t)(o - 256) * 256 + cw;
    else              src = wk + (size_t)(o - 288) * 256 + cw;
    const float4 v = *reinterpret_cast<const float4*>(src);
    __half h[4] = {__float2half(v.x), __float2half(v.y),
                   __float2half(v.z), __float2half(v.w)};
    *reinterpret_cast<uint2*>(Wh + (size_t)o * 256 + cw) =
        *reinterpret_cast<const uint2*>(h);
}

// ---------------- QKV projection via MFMA ----------------
// grid: NB*64 blocks (64-pixel tiles), 512 threads (8 waves).
// Wave w owns o-tiles {2w, 2w+1} (V channels 32w..32w+31); waves 0-3 also own
// o-tile 16+w (w=0,1: Q halves; w=2,3: K halves).
__global__ __launch_bounds__(512) void qkv_mfma(
    const float* __restrict__ x, const __half* __restrict__ Wh,
    const float* __restrict__ bq, const float* __restrict__ bk,
    const float* __restrict__ bv,
    __half* __restrict__ Qh, __half* __restrict__ Kh, __half* __restrict__ VTh)
{
    __shared__ __align__(16) __half sm[CC * VSTR];   // 36864 B; xT aliases vres
    __half* xT   = sm;                               // [64][XSTR] (33792 B)
    __half* vres = sm;                               // [256][VSTR]

    const int t  = threadIdx.x;
    const int b  = blockIdx.x >> 6;
    const int n0 = (blockIdx.x & 63) << 6;

    // ---- stage x[256c][64n] f32 -> xT[n][c] f16 (coalesced loads, b16 scatter) ----
    {
        const int nl4 = t & 15;          // float4 group along n
        const int c0  = t >> 4;          // 0..31
        const float* xp = x + ((size_t)b * CC) * NPIX + n0 + nl4 * 4;
        #pragma unroll
        for (int i = 0; i < 8; ++i) {
            const int c = c0 + 32 * i;
            const float4 v = *reinterpret_cast<const float4*>(xp + (size_t)c * NPIX);
            xT[(nl4 * 4 + 0) * XSTR + c] = __float2half(v.x);
            xT[(nl4 * 4 + 1) * XSTR + c] = __float2half(v.y);
            xT[(nl4 * 4 + 2) * XSTR + c] = __float2half(v.z);
            xT[(nl4 * 4 + 3) * XSTR + c] = __float2half(v.w);
        }
    }
    __syncthreads();

    const int w = t >> 6, l = t & 63, lr = l & 15, s = l >> 4;
    const int nto = (w < 4) ? 3 : 2;
    const int ob0 = 32 * w, ob1 = 32 * w + 16, ob2 = 256 + 16 * w;

    // ---- W fragments (global, L2-hot) ----
    f16x8 wf[3][8];
    #pragma unroll
    for (int kk = 0; kk < 8; ++kk) {
        wf[0][kk] = *reinterpret_cast<const f16x8*>(
            Wh + (size_t)(ob0 + lr) * 256 + kk * 32 + s * 8);
        wf[1][kk] = *reinterpret_cast<const f16x8*>(
            Wh + (size_t)(ob1 + lr) * 256 + kk * 32 + s * 8);
    }
    if (w < 4)
        #pragma unroll
        for (int kk = 0; kk < 8; ++kk)
            wf[2][kk] = *reinterpret_cast<const f16x8*>(
                Wh + (size_t)(ob2 + lr) * 256 + kk * 32 + s * 8);

    f32x4 acc[3][4];
    #pragma unroll
    for (int j = 0; j < 3; ++j)
        #pragma unroll
        for (int nt = 0; nt < 4; ++nt) acc[j][nt] = (f32x4){0.f, 0.f, 0.f, 0.f};

    // ---- GEMM: acc[nt][o-tile], D row = n_local = s*4+r, D col = o_local = lr ----
    #pragma unroll
    for (int nt = 0; nt < 4; ++nt) {
        f16x8 xf[8];
        #pragma unroll
        for (int kk = 0; kk < 8; ++kk)
            xf[kk] = *reinterpret_cast<const f16x8*>(
                &xT[(nt * 16 + lr) * XSTR + kk * 32 + s * 8]);
        #pragma unroll
        for (int j = 0; j < 3; ++j)
            if (j < nto)
                #pragma unroll
                for (int kk = 0; kk < 8; ++kk)
                    acc[j][nt] = __builtin_amdgcn_mfma_f32_16x16x32_f16(
                        xf[kk], wf[j][kk], acc[j][nt], 0, 0, 0);
    }

    // ---- Q/K epilogue: direct b16 stores, bias fused ----
    if (w < 4) {
        const bool is_q = (w < 2);
        const int oc = (w & 1) * 16 + lr;
        __half* dst = is_q ? Qh : Kh;
        const float bias = (is_q ? bq : bk)[oc];
        #pragma unroll
        for (int nt = 0; nt < 4; ++nt)
            #pragma unroll
            for (int r = 0; r < 4; ++r) {
                const size_t n = (size_t)b * NPIX + n0 + nt * 16 + s * 4 + r;
                dst[n * QKC + oc] = __float2half(acc[2][nt][r] + bias);
            }
    }

    // ---- V epilogue: restage through LDS (aliased), coalesced global writes ----
    __syncthreads();    // all xT reads done before vres overwrite
    {
        #pragma unroll
        for (int j = 0; j < 2; ++j) {
            const int c = 32 * w + 16 * j + lr;
            const float bias = bv[c];
            #pragma unroll
            for (int nt = 0; nt < 4; ++nt) {
                __half h[4];
                #pragma unroll
                for (int r = 0; r < 4; ++r) h[r] = __float2half(acc[j][nt][r] + bias);
                *reinterpret_cast<uint2*>(&vres[c * VSTR + nt * 16 + s * 4]) =
                    *reinterpret_cast<const uint2*>(h);
            }
        }
    }
    __syncthreads();
    {
        const int c = t >> 1, half = t & 1;
        __half* dst = VTh + ((size_t)(b * CC + c)) * NPIX + n0 + half * 32;
        #pragma unroll
        for (int jj = 0; jj < 4; ++jj)
            *reinterpret_cast<uint4*>(dst + jj * 8) =
                *reinterpret_cast<const uint4*>(&vres[c * VSTR + half * 32 + jj * 8]);
    }
}

// ---------------- MFMA flash attention: 4 S waves + 4 PV waves ----------------
// grid: 256 blocks x 512 threads. Block = (b, 64 q rows).
// Waves 0-3: S^T + softmax for q-tile w (pipelined one KV-tile ahead).
// Waves 4-7: PV for c-channels [64*(w-4), 64*(w-4)+64).
__global__ __launch_bounds__(512) void attn_mfma(
    const __half* __restrict__ Qh, const __half* __restrict__ Kh,
    const __half* __restrict__ VTh, const float* __restrict__ x,
    const float* __restrict__ gamma, float* __restrict__ out)
{
    __shared__ unsigned char Praw[2][64 * 128];   // P f16, swizzled, dbuf (16 KB)
    __shared__ float abuf[2][64];
    __shared__ float lbuf[64];

    const int t  = threadIdx.x;
    const int w  = t >> 6;
    const int l  = t & 63;
    const int lr = l & 15;
    const int s  = l >> 4;

    const int blk = (blockIdx.x & 7) * 32 + (blockIdx.x >> 3);
    const int b  = blk >> 6;
    const int n0 = (blk & 63) << 6;

    // ---- S-wave state ----
    const int qw = w * 16 + lr;                  // q row (valid for w<4)
    f16x8 qfrag;
    f16x8 kf[4];
    float m_run = -1e30f, l_run = 0.f;
    const __half* kbase = Kh + ((size_t)b * NPIX + lr) * QKC + s * 8;

    // ---- PV-wave state: 4 c-tiles of 16 ----
    const int cbase = 64 * (w - 4);
    const __half* vbase = VTh + ((size_t)(b * CC + cbase + lr)) * NPIX + s * 8;
    f16x8 vfc[4][2], vfn[4][2];
    f32x4 O[4][4];
    #pragma unroll
    for (int ct = 0; ct < 4; ++ct)
        #pragma unroll
        for (int qt = 0; qt < 4; ++qt)
            O[ct][qt] = (f32x4){0.f, 0.f, 0.f, 0.f};

    auto do_softmax = [&](int bw) {
        f32x4 sacc[4];
        #pragma unroll
        for (int mt = 0; mt < 4; ++mt)
            sacc[mt] = __builtin_amdgcn_mfma_f32_16x16x32_f16(
                kf[mt], qfrag, (f32x4){0.f, 0.f, 0.f, 0.f}, 0, 0, 0);
        float tmax = sacc[0][0];
        #pragma unroll
        for (int mt = 0; mt < 4; ++mt)
            #pragma unroll
            for (int r = 0; r < 4; ++r) tmax = fmaxf(tmax, sacc[mt][r]);
        tmax = fmaxf(tmax, __shfl_xor(tmax, 16));
        tmax = fmaxf(tmax, __shfl_xor(tmax, 32));
        const float mnew = fmaxf(m_run, tmax);
        const float al   = __expf(m_run - mnew);
        float p[4][4];
        float lsum = 0.f;
        #pragma unroll
        for (int mt = 0; mt < 4; ++mt)
            #pragma unroll
            for (int r = 0; r < 4; ++r) {
                p[mt][r] = __expf(sacc[mt][r] - mnew);
                lsum += p[mt][r];
            }
        lsum += __shfl_xor(lsum, 16);
        lsum += __shfl_xor(lsum, 32);
        l_run = al * l_run + lsum;
        m_run = mnew;
        unsigned char* pb = &Praw[bw][0];
        #pragma unroll
        for (int mt = 0; mt < 4; ++mt) {
            const int g = ((s >> 1) + 2 * mt) ^ (qw & 7);
            const __half2 u0 = __floats2half2_rn(p[mt][0], p[mt][1]);
            const __half2 u1 = __floats2half2_rn(p[mt][2], p[mt][3]);
            *reinterpret_cast<__half2*>(pb + qw * 128 + g * 16 + (s & 1) * 8)     = u0;
            *reinterpret_cast<__half2*>(pb + qw * 128 + g * 16 + (s & 1) * 8 + 4) = u1;
        }
        if (l < 16) abuf[bw][qw] = al;
    };

    // ---- prologue ----
    if (w < 4) {
        qfrag = *reinterpret_cast<const f16x8*>(
            Qh + ((size_t)b * NPIX + n0 + qw) * QKC + s * 8);
        #pragma unroll
        for (int mt = 0; mt < 4; ++mt)
            kf[mt] = *reinterpret_cast<const f16x8*>(kbase + (size_t)(mt * 16) * QKC);
        do_softmax(0);
        #pragma unroll
        for (int mt = 0; mt < 4; ++mt)
            kf[mt] = *reinterpret_cast<const f16x8*>(kbase + (size_t)(64 + mt * 16) * QKC);
    } else {
        #pragma unroll
        for (int ct = 0; ct < 4; ++ct)
            #pragma unroll
            for (int ks = 0; ks < 2; ++ks)
                vfc[ct][ks] = *reinterpret_cast<const f16x8*>(
                    vbase + (size_t)ct * 16 * NPIX + ks * 32);
    }
    __syncthreads();

    // ---- main loop ----
    for (int step = 0; step < 64; ++step) {
        const int pbuf = step & 1;
        if (w < 4) {
            if (step < 63) {
                do_softmax(pbuf ^ 1);
                if (step < 62) {
                    const size_t moff = (size_t)((step + 2) * 64) * QKC;
                    #pragma unroll
                    for (int mt = 0; mt < 4; ++mt)
                        kf[mt] = *reinterpret_cast<const f16x8*>(
                            kbase + moff + (size_t)(mt * 16) * QKC);
                }
            }
        } else {
            if (step < 63) {
                const size_t moff = (size_t)((step + 1) * 64);
                #pragma unroll
                for (int ct = 0; ct < 4; ++ct)
                    #pragma unroll
                    for (int ks = 0; ks < 2; ++ks)
                        vfn[ct][ks] = *reinterpret_cast<const f16x8*>(
                            vbase + (size_t)ct * 16 * NPIX + moff + ks * 32);
            }
            float av[4];
            #pragma unroll
            for (int qt = 0; qt < 4; ++qt) av[qt] = abuf[pbuf][qt * 16 + lr];
            #pragma unroll
            for (int ct = 0; ct < 4; ++ct)
                #pragma unroll
                for (int qt = 0; qt < 4; ++qt)
                    #pragma unroll
                    for (int r = 0; r < 4; ++r) O[ct][qt][r] *= av[qt];

            const unsigned char* pr = &Praw[pbuf][0];
            #pragma unroll
            for (int qt = 0; qt < 4; ++qt) {
                const int q2 = qt * 16 + lr;
                const int g0 = s ^ (q2 & 7);
                const int g1 = (s + 4) ^ (q2 & 7);
                const f16x8 pf0 = *reinterpret_cast<const f16x8*>(pr + q2 * 128 + g0 * 16);
                const f16x8 pf1 = *reinterpret_cast<const f16x8*>(pr + q2 * 128 + g1 * 16);
                #pragma unroll
                for (int ct = 0; ct < 4; ++ct) {
                    O[ct][qt] = __builtin_amdgcn_mfma_f32_16x16x32_f16(
                        vfc[ct][0], pf0, O[ct][qt], 0, 0, 0);
                    O[ct][qt] = __builtin_amdgcn_mfma_f32_16x16x32_f16(
                        vfc[ct][1], pf1, O[ct][qt], 0, 0, 0);
                }
            }
            if (step < 63) {
                #pragma unroll
                for (int ct = 0; ct < 4; ++ct)
                    #pragma unroll
                    for (int ks = 0; ks < 2; ++ks) vfc[ct][ks] = vfn[ct][ks];
            }
        }
        __syncthreads();
    }

    // ---- epilogue ----
    if (w < 4) { if (l < 16) lbuf[qw] = l_run; }
    __syncthreads();
    if (w >= 4) {
        const float g = gamma[0];
        float linv[4];
        #pragma unroll
        for (int qt = 0; qt < 4; ++qt) linv[qt] = g / lbuf[qt * 16 + lr];
        #pragma unroll
        for (int ct = 0; ct < 4; ++ct)
            #pragma unroll
            for (int qt = 0; qt < 4; ++qt)
                #pragma unroll
                for (int r = 0; r < 4; ++r) {
                    const int c = cbase + ct * 16 + s * 4 + r;
                    const size_t idx = ((size_t)(b * CC + c)) * NPIX + n0 + qt * 16 + lr;
                    out[idx] = O[ct][qt][r] * linv[qt] + x[idx];
                }
    }
}

extern "C" void kernel_launch(void* const* d_in, const int* in_sizes, int n_in,
                              void* d_out, int out_size, void* d_ws, size_t ws_size,
                              hipStream_t stream) {
    const float* x     = (const float*)d_in[0];
    const float* wq    = (const float*)d_in[1];
    const float* bq    = (const float*)d_in[2];
    const float* wk    = (const float*)d_in[3];
    const float* bk    = (const float*)d_in[4];
    const float* wv    = (const float*)d_in[5];
    const float* bv    = (const float*)d_in[6];
    const float* gamma = (const float*)d_in[7];
    float* out = (float*)d_out;

    // ws (f16): Wh [320][256] | Qh [B][N][32] | Kh [B][N][32] | VTh [B][C][N]
    __half* Wh  = (__half*)d_ws;
    __half* Qh  = Wh + (size_t)320 * 256;
    __half* Kh  = Qh + (size_t)NB * NPIX * QKC;
    __half* VTh = Kh + (size_t)NB * NPIX * QKC;

    hipLaunchKernelGGL(wh_prep, dim3(80), dim3(256), 0, stream, wq, wk, wv, Wh);
    hipLaunchKernelGGL(qkv_mfma, dim3(NB * 64), dim3(512), 0, stream,
                       x, Wh, bq, bk, bv, Qh, Kh, VTh);
    hipLaunchKernelGGL(attn_mfma, dim3(256), dim3(512), 0, stream,
                       Qh, Kh, VTh, x, gamma, out);
}